// Round 1
// baseline (135.367 us; speedup 1.0000x reference)
//
#include <hip/hip_runtime.h>
#include <math.h>

// Problem constants
#define IMN   256          // image size per dim
#define KDIM  512          // oversampled grid per dim
#define JT    6            // KB taps per dim
#define LTAB  1024         // table oversampling
#define MPTS  65536        // samples per batch
#define NB    2            // batches
#define NC    8            // coils
#define NIMG  (NB*NC)      // 16 images

__device__ __forceinline__ int rev9(int v) {
    return (int)(__brev((unsigned)v) >> 23);   // 9-bit bit-reversal (v < 512)
}

// ---------------------------------------------------------------------------
// Pass 1: per (image, row<256): img = (x * smap) * sn / 512, zero-pad to 512,
// 512-pt FFT along columns-within-row, write row to grid[ic][row][0..511].
// ---------------------------------------------------------------------------
__global__ __launch_bounds__(256) void rowfft_kernel(
    const float* __restrict__ x, const float* __restrict__ smap,
    const float* __restrict__ sn, float2* __restrict__ grid)
{
    int row = blockIdx.x;          // 0..255
    int ic  = blockIdx.y;          // 0..15
    int b = ic >> 3, c = ic & 7;
    int t = threadIdx.x;           // 0..255

    __shared__ float2 lds[512];

    int base = row * IMN + t;
    float xr = x[(b*2 + 0) * (IMN*IMN) + base];
    float xi = x[(b*2 + 1) * (IMN*IMN) + base];
    float sr = smap[((b*NC + c)*2 + 0) * (IMN*IMN) + base];
    float si = smap[((b*NC + c)*2 + 1) * (IMN*IMN) + base];
    float s  = sn[base] * (1.0f / 512.0f);   // 1/sqrt(512*512) folded in here

    float2 v;
    v.x = (xr*sr - xi*si) * s;
    v.y = (xr*si + xi*sr) * s;

    int rc = rev9(t);              // even (bit8 of t is 0)
    lds[rc]     = v;
    lds[rc | 1] = make_float2(0.f, 0.f);   // zero-pad columns 256..511
    __syncthreads();

    #pragma unroll
    for (int s9 = 1; s9 <= 9; ++s9) {
        int mh  = 1 << (s9 - 1);
        int g   = t >> (s9 - 1);
        int k   = t & (mh - 1);
        int idx = (g << s9) + k;
        float ang = -3.14159265358979f * (float)k / (float)mh;
        float sw, cw;
        __sincosf(ang, &sw, &cw);
        float2 u = lds[idx];
        float2 w = lds[idx + mh];
        float tr = w.x*cw - w.y*sw;
        float ti = w.x*sw + w.y*cw;
        lds[idx]      = make_float2(u.x + tr, u.y + ti);
        lds[idx + mh] = make_float2(u.x - tr, u.y - ti);
        __syncthreads();
    }

    float2* orow = grid + ((size_t)ic * KDIM + row) * KDIM;
    orow[t]       = lds[t];
    orow[t + 256] = lds[t + 256];
}

// ---------------------------------------------------------------------------
// Pass 2: column FFTs, 8 columns per block staged in LDS. Rows 256..511 of
// the input are implicitly zero (pass 1 only wrote rows 0..255).
// ---------------------------------------------------------------------------
__global__ __launch_bounds__(256) void colfft_kernel(float2* __restrict__ grid)
{
    int tile = blockIdx.x;         // 0..63 -> col0 = tile*8
    int ic   = blockIdx.y;         // 0..15
    int t    = threadIdx.x;        // 0..255

    __shared__ float2 lds[8][512]; // 32 KB

    int cc = t & 7;                // column within tile
    int rb = t >> 3;               // 0..31
    float2* img = grid + (size_t)ic * KDIM * KDIM;
    int col0 = tile * 8;

    #pragma unroll
    for (int it = 0; it < 8; ++it) {
        int r = it * 32 + rb;      // 0..255
        float2 v = img[(size_t)r * KDIM + col0 + cc];
        int rr = rev9(r);
        lds[cc][rr]     = v;
        lds[cc][rr | 1] = make_float2(0.f, 0.f);   // zero-pad rows 256..511
    }
    __syncthreads();

    #pragma unroll
    for (int s9 = 1; s9 <= 9; ++s9) {
        int mh  = 1 << (s9 - 1);
        int g   = t >> (s9 - 1);
        int k   = t & (mh - 1);
        int idx = (g << s9) + k;
        float ang = -3.14159265358979f * (float)k / (float)mh;
        float sw, cw;
        __sincosf(ang, &sw, &cw);
        #pragma unroll
        for (int c2 = 0; c2 < 8; ++c2) {
            float2 u = lds[c2][idx];
            float2 w = lds[c2][idx + mh];
            float tr = w.x*cw - w.y*sw;
            float ti = w.x*sw + w.y*cw;
            lds[c2][idx]      = make_float2(u.x + tr, u.y + ti);
            lds[c2][idx + mh] = make_float2(u.x - tr, u.y - ti);
        }
        __syncthreads();
    }

    #pragma unroll
    for (int it = 0; it < 16; ++it) {
        int r = it * 32 + rb;      // 0..511
        img[(size_t)r * KDIM + col0 + cc] = lds[cc][r];
    }
}

// ---------------------------------------------------------------------------
// Pass 3: KB table interpolation. One thread per (b, c, m).
// ---------------------------------------------------------------------------
__global__ __launch_bounds__(256) void interp_kernel(
    const float2* __restrict__ grid, const float* __restrict__ om,
    const float* __restrict__ tab0, const float* __restrict__ tab1,
    float* __restrict__ out)
{
    int gtid = blockIdx.x * 256 + threadIdx.x;
    if (gtid >= NB * NC * MPTS) return;
    int m = gtid & (MPTS - 1);
    int c = (gtid >> 16) & 7;
    int b = gtid >> 19;

    float om0 = om[(b*2 + 0) * MPTS + m];
    float om1 = om[(b*2 + 1) * MPTS + m];

    const float KC = 512.0f / 6.283185307179586f;   // K/(2*pi)

    float w0[6], w1[6];
    int   g0[6], g1[6];

    {
        float tm = om0 * KC;
        float koff = floorf(tm - 3.0f);
        int   ik = (int)koff;
        #pragma unroll
        for (int j = 0; j < 6; ++j) {
            float kk   = koff + (float)(j + 1);
            float dist = tm - kk;
            int tidx = (int)rintf((dist + 3.0f) * 1024.0f);   // half-to-even, matches jnp.round
            tidx = tidx < 0 ? 0 : (tidx > JT*LTAB ? JT*LTAB : tidx);
            w0[j] = tab0[tidx];
            g0[j] = (ik + j + 1) & (KDIM - 1);                // mod 512, handles negatives
        }
    }
    {
        float tm = om1 * KC;
        float koff = floorf(tm - 3.0f);
        int   ik = (int)koff;
        #pragma unroll
        for (int j = 0; j < 6; ++j) {
            float kk   = koff + (float)(j + 1);
            float dist = tm - kk;
            int tidx = (int)rintf((dist + 3.0f) * 1024.0f);
            tidx = tidx < 0 ? 0 : (tidx > JT*LTAB ? JT*LTAB : tidx);
            w1[j] = tab1[tidx];
            g1[j] = (ik + j + 1) & (KDIM - 1);
        }
    }

    const float2* plane = grid + (size_t)(b*NC + c) * KDIM * KDIM;
    float accr = 0.f, acci = 0.f;
    #pragma unroll
    for (int i = 0; i < 6; ++i) {
        const float2* rowp = plane + (size_t)g0[i] * KDIM;
        float wi = w0[i];
        #pragma unroll
        for (int j = 0; j < 6; ++j) {
            float2 v = rowp[g1[j]];
            float w  = wi * w1[j];
            accr = fmaf(w, v.x, accr);
            acci = fmaf(w, v.y, acci);
        }
    }

    // phase = exp(i*(om0*128 + om1*128)); use accurate sincosf (large argument)
    float ph = (om0 + om1) * 128.0f;
    float sp, cp;
    sincosf(ph, &sp, &cp);
    float yr = accr*cp - acci*sp;
    float yi = accr*sp + acci*cp;

    out[((size_t)(b*NC + c)*2 + 0) * MPTS + m] = yr;
    out[((size_t)(b*NC + c)*2 + 1) * MPTS + m] = yi;
}

// ---------------------------------------------------------------------------
extern "C" void kernel_launch(void* const* d_in, const int* in_sizes, int n_in,
                              void* d_out, int out_size, void* d_ws, size_t ws_size,
                              hipStream_t stream) {
    const float* x    = (const float*)d_in[0];
    const float* smap = (const float*)d_in[1];
    const float* om   = (const float*)d_in[2];
    const float* sn   = (const float*)d_in[3];
    const float* tab0 = (const float*)d_in[4];
    const float* tab1 = (const float*)d_in[5];
    float*  out  = (float*)d_out;
    float2* grid = (float2*)d_ws;   // 16 * 512 * 512 * 8B = 32 MB

    dim3 gA(IMN, NIMG);
    rowfft_kernel<<<gA, 256, 0, stream>>>(x, smap, sn, grid);

    dim3 gB(KDIM / 8, NIMG);
    colfft_kernel<<<gB, 256, 0, stream>>>(grid);

    interp_kernel<<<(NB*NC*MPTS) / 256, 256, 0, stream>>>(grid, om, tab0, tab1, out);
}

// Round 2
// 85.076 us; speedup vs baseline: 1.5911x; 1.5911x over previous
//
#include <hip/hip_runtime.h>
#include <math.h>

// Problem constants
#define IMN   256          // image size per dim
#define KDIM  512          // oversampled grid per dim
#define JT    6            // KB taps per dim
#define LTAB  1024         // table oversampling
#define MPTS  65536        // samples per batch
#define NB    2            // batches
#define NC    8            // coils
#define NIMG  (NB*NC)      // 16 images

__device__ __forceinline__ int rev9(int v) {
    return (int)(__brev((unsigned)v) >> 23);   // 9-bit bit-reversal (v < 512)
}

// ---------------------------------------------------------------------------
// Pass 1: column FFTs. Per block: one (ic), 8 image-columns. Fuses the
// apodization img = (x*smap)*sn/512. Input columns 0..255 zero-padded to 512.
// Output: tmp[ic][kr][col] (transposed planar, [16][512][256] float2 = 16 MB),
// written in fully-used 64B chunks.
// ---------------------------------------------------------------------------
__global__ __launch_bounds__(256) void fft_cols(
    const float* __restrict__ x, const float* __restrict__ smap,
    const float* __restrict__ sn, float2* __restrict__ tmp)
{
    int ctile = blockIdx.x;        // 0..31 -> col0 = ctile*8
    int ic    = blockIdx.y;        // 0..15
    int b = ic >> 3, c = ic & 7;
    int t = threadIdx.x;           // 0..255

    __shared__ float2 lds[8][516]; // pad row stride to 516 (bank spread)

    int cc = t & 7;                // column within tile
    int rg = t >> 3;               // 0..31
    int col = ctile * 8 + cc;

    #pragma unroll
    for (int it = 0; it < 8; ++it) {
        int r = it * 32 + rg;      // image row 0..255
        int pix = r * IMN + col;
        float xr = x[(b*2 + 0) * (IMN*IMN) + pix];
        float xi = x[(b*2 + 1) * (IMN*IMN) + pix];
        float sr = smap[((b*NC + c)*2 + 0) * (IMN*IMN) + pix];
        float si = smap[((b*NC + c)*2 + 1) * (IMN*IMN) + pix];
        float s  = sn[pix] * (1.0f / 512.0f);   // 1/sqrt(512*512)
        float2 v;
        v.x = (xr*sr - xi*si) * s;
        v.y = (xr*si + xi*sr) * s;
        int rr = rev9(r);          // even (bit8 of r is 0)
        lds[cc][rr]     = v;
        lds[cc][rr | 1] = make_float2(0.f, 0.f);  // zero-pad rows 256..511
    }
    __syncthreads();

    #pragma unroll
    for (int s9 = 1; s9 <= 9; ++s9) {
        int mh  = 1 << (s9 - 1);
        int g   = t >> (s9 - 1);
        int k   = t & (mh - 1);
        int idx = (g << s9) + k;
        float ang = -3.14159265358979f * (float)k / (float)mh;
        float sw, cw;
        __sincosf(ang, &sw, &cw);
        #pragma unroll
        for (int c2 = 0; c2 < 8; ++c2) {
            float2 u = lds[c2][idx];
            float2 w = lds[c2][idx + mh];
            float tr = w.x*cw - w.y*sw;
            float ti = w.x*sw + w.y*cw;
            lds[c2][idx]      = make_float2(u.x + tr, u.y + ti);
            lds[c2][idx + mh] = make_float2(u.x - tr, u.y - ti);
        }
        __syncthreads();
    }

    #pragma unroll
    for (int it = 0; it < 16; ++it) {
        int kr = it * 32 + rg;     // 0..511
        tmp[((size_t)ic * KDIM + kr) * IMN + col] = lds[cc][kr];
    }
}

// ---------------------------------------------------------------------------
// Pass 2: row FFTs. Per block: one (b, kr), all 8 coils. Reads tmp rows
// contiguously (2KB per coil), zero-pads cols 256..511, FFTs, and writes the
// COIL-INTERLEAVED final grid: gridI[b][kr][kc][coil] as one contiguous 32KB
// block.
// ---------------------------------------------------------------------------
__global__ __launch_bounds__(256) void fft_rows(
    const float2* __restrict__ tmp, float2* __restrict__ gridI)
{
    int kr = blockIdx.x;           // 0..511
    int b  = blockIdx.y;           // 0..1
    int t  = threadIdx.x;          // 0..255

    __shared__ float2 lds[8][516];

    int cl = t >> 5;               // coil 0..7
    int i0 = t & 31;

    #pragma unroll
    for (int it = 0; it < 8; ++it) {
        int idx = it * 32 + i0;    // 0..255
        float2 v = tmp[((size_t)(b*NC + cl) * KDIM + kr) * IMN + idx];
        int rr = rev9(idx);
        lds[cl][rr]     = v;
        lds[cl][rr | 1] = make_float2(0.f, 0.f);  // zero-pad cols 256..511
    }
    __syncthreads();

    #pragma unroll
    for (int s9 = 1; s9 <= 9; ++s9) {
        int mh  = 1 << (s9 - 1);
        int g   = t >> (s9 - 1);
        int k   = t & (mh - 1);
        int idx = (g << s9) + k;
        float ang = -3.14159265358979f * (float)k / (float)mh;
        float sw, cw;
        __sincosf(ang, &sw, &cw);
        #pragma unroll
        for (int c2 = 0; c2 < 8; ++c2) {
            float2 u = lds[c2][idx];
            float2 w = lds[c2][idx + mh];
            float tr = w.x*cw - w.y*sw;
            float ti = w.x*sw + w.y*cw;
            lds[c2][idx]      = make_float2(u.x + tr, u.y + ti);
            lds[c2][idx + mh] = make_float2(u.x - tr, u.y - ti);
        }
        __syncthreads();
    }

    // interleaved write: 4096 float2 = 32 KB contiguous
    float2* o = gridI + ((size_t)(b * KDIM + kr) * KDIM) * NC;
    #pragma unroll
    for (int it = 0; it < 16; ++it) {
        int idx = it * 256 + t;    // 0..4095
        int kc  = idx >> 3;
        int c   = idx & 7;
        o[idx] = lds[c][kc];
    }
}

// ---------------------------------------------------------------------------
// Pass 3: KB interpolation on the interleaved grid. 2 threads per (b,m):
// lane pair consumes the two 32B halves of each 64B cell (4 coils each).
// ---------------------------------------------------------------------------
__global__ __launch_bounds__(256) void interp2(
    const float2* __restrict__ gridI, const float* __restrict__ om,
    const float* __restrict__ tab0, const float* __restrict__ tab1,
    float* __restrict__ out)
{
    int gt   = blockIdx.x * 256 + threadIdx.x;   // 0..262143
    int half = gt & 1;            // coil group: 0 -> coils 0..3, 1 -> 4..7
    int p    = gt >> 1;           // 0..131071
    int m    = p & (MPTS - 1);
    int b    = p >> 16;

    float om0 = om[(b*2 + 0) * MPTS + m];
    float om1 = om[(b*2 + 1) * MPTS + m];

    const float KC = 512.0f / 6.283185307179586f;   // K/(2*pi)

    float w0[6], w1[6];
    int   g0[6], g1[6];
    {
        float tm = om0 * KC;
        float koff = floorf(tm - 3.0f);
        int   ik = (int)koff;
        #pragma unroll
        for (int j = 0; j < 6; ++j) {
            float kk   = koff + (float)(j + 1);
            float dist = tm - kk;
            int tidx = (int)rintf((dist + 3.0f) * 1024.0f);   // half-to-even = jnp.round
            tidx = tidx < 0 ? 0 : (tidx > JT*LTAB ? JT*LTAB : tidx);
            w0[j] = tab0[tidx];
            g0[j] = (ik + j + 1) & (KDIM - 1);                // mod 512 incl. negatives
        }
    }
    {
        float tm = om1 * KC;
        float koff = floorf(tm - 3.0f);
        int   ik = (int)koff;
        #pragma unroll
        for (int j = 0; j < 6; ++j) {
            float kk   = koff + (float)(j + 1);
            float dist = tm - kk;
            int tidx = (int)rintf((dist + 3.0f) * 1024.0f);
            tidx = tidx < 0 ? 0 : (tidx > JT*LTAB ? JT*LTAB : tidx);
            w1[j] = tab1[tidx];
            g1[j] = (ik + j + 1) & (KDIM - 1);
        }
    }

    const float* plane = (const float*)(gridI + (size_t)b * KDIM * KDIM * NC) + half * 8;
    float ar[4] = {0.f,0.f,0.f,0.f}, ai[4] = {0.f,0.f,0.f,0.f};

    #pragma unroll
    for (int i = 0; i < 6; ++i) {
        const float* rp = plane + (size_t)g0[i] * (KDIM * NC * 2);
        float wi = w0[i];
        #pragma unroll
        for (int j = 0; j < 6; ++j) {
            const float* cp = rp + g1[j] * (NC * 2);   // 32B-aligned half-cell
            float w = wi * w1[j];
            float4 v01 = *(const float4*)(cp);         // coils h4+0, h4+1 (re,im)
            float4 v23 = *(const float4*)(cp + 4);     // coils h4+2, h4+3
            ar[0] = fmaf(w, v01.x, ar[0]); ai[0] = fmaf(w, v01.y, ai[0]);
            ar[1] = fmaf(w, v01.z, ar[1]); ai[1] = fmaf(w, v01.w, ai[1]);
            ar[2] = fmaf(w, v23.x, ar[2]); ai[2] = fmaf(w, v23.y, ai[2]);
            ar[3] = fmaf(w, v23.z, ar[3]); ai[3] = fmaf(w, v23.w, ai[3]);
        }
    }

    float ph = (om0 + om1) * 128.0f;
    float sp, cp;
    sincosf(ph, &sp, &cp);   // accurate (large argument)

    #pragma unroll
    for (int k = 0; k < 4; ++k) {
        int c = half * 4 + k;
        float yr = ar[k]*cp - ai[k]*sp;
        float yi = ar[k]*sp + ai[k]*cp;
        out[((size_t)(b*NC + c)*2 + 0) * MPTS + m] = yr;
        out[((size_t)(b*NC + c)*2 + 1) * MPTS + m] = yi;
    }
}

// ---------------------------------------------------------------------------
extern "C" void kernel_launch(void* const* d_in, const int* in_sizes, int n_in,
                              void* d_out, int out_size, void* d_ws, size_t ws_size,
                              hipStream_t stream) {
    const float* x    = (const float*)d_in[0];
    const float* smap = (const float*)d_in[1];
    const float* om   = (const float*)d_in[2];
    const float* sn   = (const float*)d_in[3];
    const float* tab0 = (const float*)d_in[4];
    const float* tab1 = (const float*)d_in[5];
    float* out = (float*)d_out;

    // ws layout: [0, 32MB) interleaved grid; [32MB, 48MB) transposed tmp
    float2* gridI = (float2*)d_ws;                              // 2*512*512*8 float2
    float2* tmp   = (float2*)((char*)d_ws + (size_t)32*1024*1024);  // 16*512*256 float2

    dim3 g1(IMN/8, NIMG);          // 32 x 16
    fft_cols<<<g1, 256, 0, stream>>>(x, smap, sn, tmp);

    dim3 g2(KDIM, NB);             // 512 x 2
    fft_rows<<<g2, 256, 0, stream>>>(tmp, gridI);

    interp2<<<(2*NB*MPTS) / 256, 256, 0, stream>>>(gridI, om, tab0, tab1, out);
}